// Round 2
// baseline (123.578 us; speedup 1.0000x reference)
//
#include <hip/hip_runtime.h>
#include <math.h>

#define BIGV 10000000000.0f
#define WA   0.096f

// Kernel 1: z-pass for all 3 labels at once.
// Grid (y=64, b=2, ihalf=2), 256 threads. Each wave computes 8 output-z rows
// for 3 label fields. D layout: [b*3+L][z][y][x], fp32, 64^3 each.
__global__ __launch_bounds__(256) void pass_z_kernel(const int* __restrict__ lab,
                                                     float* __restrict__ D) {
    const int ys = blockIdx.x, b = blockIdx.y, ih = blockIdx.z;
    const int lane = threadIdx.x & 63;
    const int wv   = threadIdx.x >> 6;

    __shared__ int sl[64][64];                 // [z][x]
    const int* lp = lab + b * 262144 + ys * 64;
    for (int z = wv; z < 64; z += 4)
        sl[z][lane] = lp[z * 4096 + lane];
    __syncthreads();

    const int i0 = ih * 32 + wv * 8;
    float m0[8], m1[8], m2[8];
#pragma unroll
    for (int ii = 0; ii < 8; ++ii) m0[ii] = m1[ii] = m2[ii] = __builtin_inff();

    for (int j = 0; j < 64; ++j) {
        const int lv = sl[j][lane];
        const float v0 = (lv == 0) ? 0.0f : BIGV;
        const float v1 = (lv == 1) ? 0.0f : BIGV;
        const float v2 = (lv == 2) ? 0.0f : BIGV;
        const float fb = (float)(i0 - j);
#pragma unroll
        for (int ii = 0; ii < 8; ++ii) {
            const float t = WA * (fb + (float)ii);   // 0.096*(i-j), exact int diff
            m0[ii] = fminf(m0[ii], __builtin_fmaf(t, t, v0));
            m1[ii] = fminf(m1[ii], __builtin_fmaf(t, t, v1));
            m2[ii] = fminf(m2[ii], __builtin_fmaf(t, t, v2));
        }
    }

    float* Dp = D + b * 3 * 262144 + ys * 64;
#pragma unroll
    for (int ii = 0; ii < 8; ++ii) {
        const int zo = (i0 + ii) * 4096 + lane;
        Dp[zo]              = m0[ii];
        Dp[262144 + zo]     = m1[ii];
        Dp[2 * 262144 + zo] = m2[ii];
    }
}

// Kernel 2: fused y-pass + x-pass + penalty + global reduction.
// Grid (z=64, b=2, yhalf=2), 256 threads. Block stages the (y,x) slices of all
// 3 fields at its z (48 KB LDS), y-pass into registers (lane = x), x-pass via
// __shfl within the wave, then combines with labels/x and atomicAdds.
__global__ __launch_bounds__(256) void pass_yx_kernel(const float* __restrict__ x,
                                                      const int* __restrict__ lab,
                                                      const float* __restrict__ D,
                                                      float* __restrict__ out) {
    const int z = blockIdx.x, b = blockIdx.y, yh = blockIdx.z;
    const int lane = threadIdx.x & 63;
    const int wv   = threadIdx.x >> 6;

    __shared__ float s[3][64][64];             // [L][y][x], 48 KB
    const float* Dp = D + b * 3 * 262144 + z * 4096;
    float* sf = &s[0][0][0];
    for (int t = threadIdx.x; t < 4096; t += 256) {
        sf[t]        = Dp[t];
        sf[4096 + t] = Dp[262144 + t];
        sf[8192 + t] = Dp[2 * 262144 + t];
    }
    __syncthreads();

    const int i0 = yh * 32 + wv * 8;           // this wave's 8 output y rows
    float m0[8], m1[8], m2[8];
#pragma unroll
    for (int ii = 0; ii < 8; ++ii) m0[ii] = m1[ii] = m2[ii] = __builtin_inff();

    for (int j = 0; j < 64; ++j) {
        const float a0 = s[0][j][lane];
        const float a1 = s[1][j][lane];
        const float a2 = s[2][j][lane];
        const float fb = (float)(i0 - j);
#pragma unroll
        for (int ii = 0; ii < 8; ++ii) {
            const float t = WA * (fb + (float)ii);
            m0[ii] = fminf(m0[ii], __builtin_fmaf(t, t, a0));
            m1[ii] = fminf(m1[ii], __builtin_fmaf(t, t, a1));
            m2[ii] = fminf(m2[ii], __builtin_fmaf(t, t, a2));
        }
    }

    // Prefetch epilogue inputs so they overlap the x-pass compute.
    int   lv[8];
    float x1[8], x2[8];
    const int base = b * 262144 + z * 4096 + lane;
#pragma unroll
    for (int ii = 0; ii < 8; ++ii) {
        const int off = base + (i0 + ii) * 64;
        lv[ii] = lab[off];
        x1[ii] = x[262144 + b * 3 * 262144 + z * 4096 + (i0 + ii) * 64 + lane];
        x2[ii] = x[2 * 262144 + b * 3 * 262144 + z * 4096 + (i0 + ii) * 64 + lane];
    }

    // x-pass: rows live in this wave's registers, lane = x. Shuffle over j.
    float g0[8], g1[8], g2[8];
#pragma unroll
    for (int ii = 0; ii < 8; ++ii) g0[ii] = g1[ii] = g2[ii] = __builtin_inff();

    for (int j = 0; j < 64; ++j) {
        const float t   = WA * (float)(lane - j);
        const float d2v = t * t;
#pragma unroll
        for (int ii = 0; ii < 8; ++ii) {
            g0[ii] = fminf(g0[ii], __shfl(m0[ii], j) + d2v);
            g1[ii] = fminf(g1[ii], __shfl(m1[ii], j) + d2v);
            g2[ii] = fminf(g2[ii], __shfl(m2[ii], j) + d2v);
        }
    }

    float part = 0.0f;
#pragma unroll
    for (int ii = 0; ii < 8; ++ii) {
        const float d0  = (lv[ii] == 0) ? BIGV : g0[ii];
        const float d1  = (lv[ii] == 1) ? BIGV : g1[ii];
        const float d2m = (lv[ii] == 2) ? BIGV : g2[ii];
        const float dt  = sqrtf(fminf(d0, fminf(d1, d2m))) + 1.0f;
        const float t1  = (lv[ii] == 1) ? (1.0f - x1[ii]) : x1[ii];
        const float t2  = (lv[ii] == 2) ? (1.0f - x2[ii]) : x2[ii];
        part += (t1 + t2) * dt;
    }

#pragma unroll
    for (int o = 32; o; o >>= 1) part += __shfl_down(part, o);
    if (lane == 0)
        atomicAdd(out, part * (1.0f / 1048576.0f));
    if (blockIdx.x == 0 && blockIdx.y == 0 && blockIdx.z == 0 && threadIdx.x == 0)
        atomicAdd(out, 1e-5f);
}

extern "C" void kernel_launch(void* const* d_in, const int* in_sizes, int n_in,
                              void* d_out, int out_size, void* d_ws, size_t ws_size,
                              hipStream_t stream) {
    const float* x = (const float*)d_in[0];   // (2,3,64,64,64) fp32
    const int*   y = (const int*)d_in[1];     // (2,1,64,64,64) int32
    float* D   = (float*)d_ws;                // 6 * 262144 floats
    float* out = (float*)d_out;

    hipMemsetAsync(out, 0, sizeof(float), stream);
    pass_z_kernel<<<dim3(64, 2, 2), 256, 0, stream>>>(y, D);
    pass_yx_kernel<<<dim3(64, 2, 2), 256, 0, stream>>>(x, y, D, out);
}

// Round 3
// 103.042 us; speedup vs baseline: 1.1993x; 1.1993x over previous
//
#include <hip/hip_runtime.h>
#include <math.h>

#define BIGV 10000000000.0f
#define WA   0.096f

// min over j of [lab[j]==L ? 0 : BIG] + (WA*(i-j))^2  ==  (WA*dist_to_nearest_seed)^2
// computed from a 64-bit seed mask via ctz/clz. Exact match to brute force.
__device__ __forceinline__ float seed_dist2(unsigned long long mask, int i) {
    const unsigned long long mr = mask >> i;          // seeds at j >= i
    const unsigned long long ml = mask << (63 - i);   // seeds at j <= i
    const int dr = mr ? __builtin_ctzll(mr) : 1000;
    const int dl = ml ? __builtin_clzll(ml) : 1000;
    const int d  = dr < dl ? dr : dl;
    const float t = WA * (float)d;
    return (d > 63) ? BIGV : t * t;
}

// Kernel A: x-pass (ballot) + z-pass for all 3 labels, per (b, y) slice.
// Grid (y=64, b=2, zq=4), 256 threads. D layout: [b*3+L][z][y][x] fp32.
__global__ __launch_bounds__(256) void pass_xz_kernel(const int* __restrict__ lab,
                                                      float* __restrict__ D) {
    const int ys = blockIdx.x, b = blockIdx.y, zq = blockIdx.z;
    const int lane = threadIdx.x & 63;
    const int wv   = threadIdx.x >> 6;

    __shared__ float sm[3][64][64];                  // [L][z][x], 48 KB

    const int* lp = lab + b * 262144 + ys * 64;
    for (int z = wv * 16, e = z + 16; z < e; ++z) {
        const int lv = lp[z * 4096 + lane];
        const unsigned long long mk0 = __ballot(lv == 0);
        const unsigned long long mk1 = __ballot(lv == 1);
        const unsigned long long mk2 = __ballot(lv == 2);
        sm[0][z][lane] = seed_dist2(mk0, lane);
        sm[1][z][lane] = seed_dist2(mk1, lane);
        sm[2][z][lane] = seed_dist2(mk2, lane);
    }
    __syncthreads();

    const int i0 = zq * 16 + wv * 4;                 // 4 output-z rows per wave
    float m0[4], m1[4], m2[4];
#pragma unroll
    for (int ii = 0; ii < 4; ++ii) m0[ii] = m1[ii] = m2[ii] = __builtin_inff();

    for (int j = 0; j < 64; ++j) {
        const float a0 = sm[0][j][lane];
        const float a1 = sm[1][j][lane];
        const float a2 = sm[2][j][lane];
        const float fb = (float)(i0 - j);
#pragma unroll
        for (int ii = 0; ii < 4; ++ii) {
            const float t = WA * (fb + (float)ii);
            m0[ii] = fminf(m0[ii], __builtin_fmaf(t, t, a0));
            m1[ii] = fminf(m1[ii], __builtin_fmaf(t, t, a1));
            m2[ii] = fminf(m2[ii], __builtin_fmaf(t, t, a2));
        }
    }

    float* Dp = D + b * 3 * 262144 + ys * 64;
#pragma unroll
    for (int ii = 0; ii < 4; ++ii) {
        const int zo = (i0 + ii) * 4096 + lane;
        Dp[zo]              = m0[ii];
        Dp[262144 + zo]     = m1[ii];
        Dp[2 * 262144 + zo] = m2[ii];
    }
}

// Kernel B: y-pass + penalty epilogue + reduction, per (b, z) slice.
// Grid (z=64, b=2, yq=4), 256 threads.
__global__ __launch_bounds__(256) void pass_y_kernel(const float* __restrict__ x,
                                                     const int* __restrict__ lab,
                                                     const float* __restrict__ D,
                                                     float* __restrict__ out) {
    const int z = blockIdx.x, b = blockIdx.y, yq = blockIdx.z;
    const int lane = threadIdx.x & 63;
    const int wv   = threadIdx.x >> 6;

    __shared__ float sm[3][64][64];                  // [L][y][x], 48 KB
    {
        const float4* Dp4 = (const float4*)(D + b * 3 * 262144 + z * 4096);
        float4* s4 = (float4*)&sm[0][0][0];
        for (int t = threadIdx.x; t < 1024; t += 256) {
            s4[t]        = Dp4[t];
            s4[1024 + t] = Dp4[65536 + t];
            s4[2048 + t] = Dp4[131072 + t];
        }
    }
    __syncthreads();

    const int i0 = yq * 16 + wv * 4;                 // 4 output-y rows per wave
    float m0[4], m1[4], m2[4];
#pragma unroll
    for (int ii = 0; ii < 4; ++ii) m0[ii] = m1[ii] = m2[ii] = __builtin_inff();

    for (int j = 0; j < 64; ++j) {
        const float a0 = sm[0][j][lane];
        const float a1 = sm[1][j][lane];
        const float a2 = sm[2][j][lane];
        const float fb = (float)(i0 - j);
#pragma unroll
        for (int ii = 0; ii < 4; ++ii) {
            const float t = WA * (fb + (float)ii);
            m0[ii] = fminf(m0[ii], __builtin_fmaf(t, t, a0));
            m1[ii] = fminf(m1[ii], __builtin_fmaf(t, t, a1));
            m2[ii] = fminf(m2[ii], __builtin_fmaf(t, t, a2));
        }
    }

    float part = 0.0f;
#pragma unroll
    for (int ii = 0; ii < 4; ++ii) {
        const int yy  = i0 + ii;
        const int off = z * 4096 + yy * 64 + lane;
        const int lv  = lab[b * 262144 + off];
        const float x1 = x[(b * 3 + 1) * 262144 + off];
        const float x2 = x[(b * 3 + 2) * 262144 + off];
        const float d0  = (lv == 0) ? BIGV : m0[ii];
        const float d1  = (lv == 1) ? BIGV : m1[ii];
        const float d2m = (lv == 2) ? BIGV : m2[ii];
        const float dt  = sqrtf(fminf(d0, fminf(d1, d2m))) + 1.0f;
        const float t1  = (lv == 1) ? (1.0f - x1) : x1;
        const float t2  = (lv == 2) ? (1.0f - x2) : x2;
        part += (t1 + t2) * dt;
    }

#pragma unroll
    for (int o = 32; o; o >>= 1) part += __shfl_down(part, o);
    if (lane == 0)
        atomicAdd(out, part * (1.0f / 1048576.0f));
    if (blockIdx.x == 0 && blockIdx.y == 0 && blockIdx.z == 0 && threadIdx.x == 0)
        atomicAdd(out, 1e-5f);
}

extern "C" void kernel_launch(void* const* d_in, const int* in_sizes, int n_in,
                              void* d_out, int out_size, void* d_ws, size_t ws_size,
                              hipStream_t stream) {
    const float* x = (const float*)d_in[0];   // (2,3,64,64,64) fp32
    const int*   y = (const int*)d_in[1];     // (2,1,64,64,64) int32
    float* D   = (float*)d_ws;                // 6 * 262144 floats
    float* out = (float*)d_out;

    hipMemsetAsync(out, 0, sizeof(float), stream);
    pass_xz_kernel<<<dim3(64, 2, 4), 256, 0, stream>>>(y, D);
    pass_y_kernel<<<dim3(64, 2, 4), 256, 0, stream>>>(x, y, D, out);
}